// Round 12
// baseline (99.022 us; speedup 1.0000x reference)
//
#include <hip/hip_runtime.h>
#include <math.h>

#define VOCAB 32000
#define EMBED 200
#define HID   10
#define GATES 40
#define BSZ   256
#define SEQ   512
#define PF    8      // steps per prefetch block

#define RPB    64    // vocab rows per proj block
#define EPITCH 202   // eT row pitch (floats): 2-way bank alias = free
#define WROW   48    // wT row pitch (4 gate-groups x 12, b128-aligned)

__device__ __forceinline__ float rcp_fast(float x) { return __builtin_amdgcn_rcpf(x); }
__device__ __forceinline__ float exp2_fast(float x) { return __builtin_amdgcn_exp2f(x); }
__device__ __forceinline__ float readlane_f(float v, int l) {
    return __int_as_float(__builtin_amdgcn_readlane(__float_as_int(v), l));
}
// DPP quad_perm broadcast of quad-lane Q (pure VALU cross-lane, no LDS)
template <int Q>
__device__ __forceinline__ float quad_bcast(float v) {
    return __int_as_float(__builtin_amdgcn_mov_dpp(
        __float_as_int(v), Q * 0x55, 0xF, 0xF, true));
}

#define SC_SIG (-1.442695041f)   // -log2(e): sigmoid lanes
#define SC_TNH (-2.885390082f)   // -2*log2(e): tanh (g) lanes

// ---------------------------------------------------------------------------
// Kernel A: proj[v][g] = (embed[v,:] . Wih[g,:] + bias[g]) * amn[g]
// where amn[g] = -log2e (sigmoid gates i,f,o) or -2log2e (tanh gate g), so
// the LSTM chain feeds exp2 directly (no per-step scale mul).
// 500 blocks x 256 thr, 1 block/CU (90 KB LDS). Stage once: wT[k][48]
// (gate-group stride 12, 16-lane broadcast reads) + all 64 embed rows
// (coalesced float4, pitch 202 -> 2-way=free). Then 25 barrier-free chunks
// of pure FMA: thread = 1 row x 10 gates, acc in 10 regs.
// ---------------------------------------------------------------------------
__global__ __launch_bounds__(256, 1) void proj_kernel(
    const float* __restrict__ embed, const float* __restrict__ Wih,
    const float* __restrict__ bih,   const float* __restrict__ bhh,
    float* __restrict__ proj)
{
    __shared__ float eT[RPB * EPITCH];     // 51.7 KB
    __shared__ float wT[EMBED * WROW];     // 38.4 KB

    const int tid = threadIdx.x;
    const int v0  = blockIdx.x * RPB;

    // stage W transposed+padded: wT[k][(g/10)*12 + g%10] = Wih[g*EMBED+k]
    for (int idx = tid; idx < GATES * EMBED; idx += 256) {
        int g = idx / EMBED, k = idx - g * EMBED;
        wT[k * WROW + (g / 10) * 12 + (g % 10)] = Wih[idx];
    }
    // stage 64 embed rows (row stride 200 = 50 float4, contiguous block)
    {
        const float4* src = (const float4*)(embed + (size_t)v0 * EMBED);
        for (int f = tid; f < RPB * 50; f += 256) {
            float4 x = src[f];
            int r = f / 50, c = f - r * 50;
            float* dst = &eT[r * EPITCH + c * 4];
            dst[0] = x.x; dst[1] = x.y; dst[2] = x.z; dst[3] = x.w;
        }
    }
    __syncthreads();

    const int tr = tid & 63;       // vocab row within block
    const int tg = tid >> 6;       // gate group (== gate class, 10 gates)

    float acc[10];
    #pragma unroll
    for (int i = 0; i < 10; ++i) acc[i] = 0.f;

    for (int k0 = 0; k0 < EMBED; k0 += 8) {
        float2 e01 = *(const float2*)&eT[tr * EPITCH + k0];
        float2 e23 = *(const float2*)&eT[tr * EPITCH + k0 + 2];
        float2 e45 = *(const float2*)&eT[tr * EPITCH + k0 + 4];
        float2 e67 = *(const float2*)&eT[tr * EPITCH + k0 + 6];
        float e[8] = {e01.x, e01.y, e23.x, e23.y, e45.x, e45.y, e67.x, e67.y};
        #pragma unroll
        for (int kk = 0; kk < 8; ++kk) {
            const float* wr = &wT[(k0 + kk) * WROW + tg * 12];
            float4 wa = *(const float4*)(wr);
            float4 wb = *(const float4*)(wr + 4);
            float2 wc = *(const float2*)(wr + 8);
            acc[0] = fmaf(e[kk], wa.x, acc[0]);
            acc[1] = fmaf(e[kk], wa.y, acc[1]);
            acc[2] = fmaf(e[kk], wa.z, acc[2]);
            acc[3] = fmaf(e[kk], wa.w, acc[3]);
            acc[4] = fmaf(e[kk], wb.x, acc[4]);
            acc[5] = fmaf(e[kk], wb.y, acc[5]);
            acc[6] = fmaf(e[kk], wb.z, acc[6]);
            acc[7] = fmaf(e[kk], wb.w, acc[7]);
            acc[8] = fmaf(e[kk], wc.x, acc[8]);
            acc[9] = fmaf(e[kk], wc.y, acc[9]);
        }
    }

    // epilogue: bias, fold activation exp2-scale (group tg == gate class)
    const float sc = (tg == 2) ? SC_TNH : SC_SIG;
    const int gbase = tg * 10;
    float* op = &proj[(size_t)(v0 + tr) * GATES + gbase];
    #pragma unroll
    for (int i = 0; i < 5; ++i) {
        float2 o;
        o.x = (acc[2*i]   + bih[gbase + 2*i]   + bhh[gbase + 2*i])   * sc;
        o.y = (acc[2*i+1] + bih[gbase + 2*i+1] + bhh[gbase + 2*i+1]) * sc;
        *(float2*)(op + 2 * i) = o;
    }
}

// ---------------------------------------------------------------------------
// Kernel B: recurrence, quad layout + clustered prefetch. lane = 4*j + k.
// __launch_bounds__(64, 1): unlock VGPR budget so the PF=8 gather ring
// actually lives in registers (R8's VGPR=24 showed the compiler sank the
// loads back onto the serial chain -> +180 cyc/step of L2 latency).
// W_hh rows pre-scaled by the exp2 activation constant (matching proj),
// so the dot feeds exp2 directly.
// ---------------------------------------------------------------------------
__global__ __launch_bounds__(64, 1) void lstm_rec(
    const int*   __restrict__ tok,  const float* __restrict__ proj,
    const float* __restrict__ h0,   const float* __restrict__ c0,
    const float* __restrict__ Whh,
    const float* __restrict__ W1,   const float* __restrict__ b1,
    const float* __restrict__ lng,  const float* __restrict__ lnb,
    const float* __restrict__ W2,   const float* __restrict__ b2,
    float* __restrict__ out)
{
    __shared__ int tok_s[SEQ + 2 * PF];

    const int b    = blockIdx.x;
    const int lane = threadIdx.x;
    const int j0   = min(lane >> 2, HID - 1);  // hidden unit
    const int k4   = lane & 3;                 // gate class i/f/g/o
    const int gate = k4 * HID + j0;            // row in [i|f|g|o]-major order

    #pragma unroll
    for (int k = 0; k < SEQ / 64; ++k)
        tok_s[k * 64 + lane] = tok[b * SEQ + k * 64 + lane];
    if (lane < 2 * PF) tok_s[SEQ + lane] = 0;  // tail pad: safe addresses
    __syncthreads();

    // activation constants: gate class 2 (g) computes tanh via 2*sig(2x)-1
    const float am  = (k4 == 2) ? 2.f : 1.f;
    const float amc = 1.f - am;
    const float amn = (k4 == 2) ? SC_TNH : SC_SIG;

    // W_hh row, pre-scaled so dot output feeds exp2 directly
    float w[HID];
    #pragma unroll
    for (int j = 0; j < HID; ++j) w[j] = amn * Whh[gate * HID + j];

    // h state (wave-uniform after readlane), redundant c per quad
    float hs[HID];
    #pragma unroll
    for (int u = 0; u < HID; ++u) hs[u] = h0[b * HID + u];
    float c_own = c0[b * HID + j0];

    // ---- prologue: block 0 gathers in flight, block 1 tokens in regs ----
    int   tk_cur[PF], tk_nxt[PF];
    float gx_cur[PF], gx_nxt[PF];
    #pragma unroll
    for (int k = 0; k < PF; ++k) tk_cur[k] = tok_s[k];
    #pragma unroll
    for (int k = 0; k < PF; ++k) gx_cur[k] = proj[tk_cur[k] * GATES + gate];
    #pragma unroll
    for (int k = 0; k < PF; ++k) tk_nxt[k] = tok_s[PF + k];

    for (int s0 = 0; s0 < SEQ; s0 += PF) {
        // issue next block's gathers (addresses from tokens read a block ago)
        #pragma unroll
        for (int k = 0; k < PF; ++k)
            gx_nxt[k] = proj[tk_nxt[k] * GATES + gate];
        // read tokens for block s0+2*PF (pad guarantees valid indices)
        #pragma unroll
        for (int k = 0; k < PF; ++k)
            tk_cur[k] = tok_s[s0 + 2 * PF + k];

        // 8 pure-VALU steps
        #pragma unroll
        for (int k = 0; k < PF; ++k) {
            // dot (pre-scaled): 4 chains + pairwise tree
            float a0 = gx_cur[k], a1 = 0.f, a2 = 0.f, a3 = 0.f;
            a0 = fmaf(hs[0], w[0], a0); a1 = fmaf(hs[1], w[1], a1);
            a2 = fmaf(hs[2], w[2], a2); a3 = fmaf(hs[3], w[3], a3);
            a0 = fmaf(hs[4], w[4], a0); a1 = fmaf(hs[5], w[5], a1);
            a2 = fmaf(hs[6], w[6], a2); a3 = fmaf(hs[7], w[7], a3);
            a0 = fmaf(hs[8], w[8], a0); a1 = fmaf(hs[9], w[9], a1);
            float dt = (a0 + a2) + (a1 + a3);

            // val = am*sigmoid(am*acc) + (1-am); dt already = amn*acc
            float t   = exp2_fast(dt);
            float sg  = rcp_fast(1.f + t);
            float val = fmaf(am, sg, amc);

            // i,f,g,o via DPP quad broadcasts (no LDS)
            float iv = quad_bcast<0>(val);
            float fv = quad_bcast<1>(val);
            float gv = quad_bcast<2>(val);
            float ov = quad_bcast<3>(val);

            c_own = fmaf(fv, c_own, iv * gv);               // c = f*c + i*g
            float t2 = exp2_fast(c_own * SC_TNH);           // 2^(-2c*log2e)
            float th = fmaf(2.f, rcp_fast(1.f + t2), -1.f); // tanh(c)
            float h_own = ov * th;

            // h broadcast: unit u lives in lane 4u -> readlane (no LDS)
            hs[0] = readlane_f(h_own, 0);  hs[1] = readlane_f(h_own, 4);
            hs[2] = readlane_f(h_own, 8);  hs[3] = readlane_f(h_own, 12);
            hs[4] = readlane_f(h_own, 16); hs[5] = readlane_f(h_own, 20);
            hs[6] = readlane_f(h_own, 24); hs[7] = readlane_f(h_own, 28);
            hs[8] = readlane_f(h_own, 32); hs[9] = readlane_f(h_own, 36);
        }

        // rotate rings (register renames under full unroll)
        #pragma unroll
        for (int k = 0; k < PF; ++k) {
            gx_cur[k] = gx_nxt[k];
            tk_nxt[k] = tk_cur[k];
        }
    }

    // head: z = hn@W1^T + b1 ; LayerNorm(5) ; sigmoid(z@W2^T + b2)
    if (lane == 0) {
        float z[5];
        float mu = 0.f;
        #pragma unroll
        for (int m = 0; m < 5; ++m) {
            float a = b1[m];
            #pragma unroll
            for (int j = 0; j < HID; ++j) a = fmaf(hs[j], W1[m * HID + j], a);
            z[m] = a; mu += a;
        }
        mu *= 0.2f;
        float var = 0.f;
        #pragma unroll
        for (int m = 0; m < 5; ++m) { float d = z[m] - mu; var = fmaf(d, d, var); }
        var *= 0.2f;
        float rs = rsqrtf(var + 1e-5f);
        float acc = b2[0];
        #pragma unroll
        for (int m = 0; m < 5; ++m) {
            float zn = fmaf((z[m] - mu) * rs, lng[m], lnb[m]);
            acc = fmaf(zn, W2[m], acc);
        }
        out[b] = 1.f / (1.f + __expf(-acc));
    }
}

extern "C" void kernel_launch(void* const* d_in, const int* in_sizes, int n_in,
                              void* d_out, int out_size, void* d_ws, size_t ws_size,
                              hipStream_t stream) {
    const int*   tok   = (const int*)  d_in[0];
    const float* h0    = (const float*)d_in[1];
    const float* c0    = (const float*)d_in[2];
    const float* embed = (const float*)d_in[3];
    const float* Wih   = (const float*)d_in[4];
    const float* Whh   = (const float*)d_in[5];
    const float* bih   = (const float*)d_in[6];
    const float* bhh   = (const float*)d_in[7];
    const float* W1    = (const float*)d_in[8];
    const float* b1    = (const float*)d_in[9];
    const float* lng   = (const float*)d_in[10];
    const float* lnb   = (const float*)d_in[11];
    const float* W2    = (const float*)d_in[12];
    const float* b2    = (const float*)d_in[13];
    float* out  = (float*)d_out;
    float* proj = (float*)d_ws;   // VOCAB*GATES*4 = 5.12 MB

    hipLaunchKernelGGL(proj_kernel, dim3(VOCAB / RPB), dim3(256), 0, stream,
                       embed, Wih, bih, bhh, proj);
    hipLaunchKernelGGL(lstm_rec, dim3(BSZ), dim3(64), 0, stream,
                       tok, proj, h0, c0, Whh, W1, b1, lng, lnb, W2, b2, out);
}